// Round 4
// baseline (270.863 us; speedup 1.0000x reference)
//
#include <hip/hip_runtime.h>

typedef __bf16 bf16x8 __attribute__((ext_vector_type(8)));
typedef __bf16 bf16x4 __attribute__((ext_vector_type(4)));
typedef float f32x4 __attribute__((ext_vector_type(4)));
typedef unsigned short u16;
typedef unsigned int u32;

__device__ __forceinline__ u16 f2bf(float f) {
  u32 u = __builtin_bit_cast(u32, f);
  u = (u + 0x7FFFu + ((u >> 16) & 1u)) >> 16;
  return (u16)u;
}

__device__ __forceinline__ void gload_lds16(const void* g, void* l) {
  __builtin_amdgcn_global_load_lds((const __attribute__((address_space(1))) void*)g,
                                   (__attribute__((address_space(3))) void*)l, 16, 0, 0);
}

// ---------------------------------------------------------------------------
// Transpose + cast: src fp32 [b][1024 i][1024 n] -> dst bf16 [b][1024 n][1024 i]
// grid (16 n-tiles, 16 i-tiles, 8 b), block 256
// ---------------------------------------------------------------------------
__global__ __launch_bounds__(256) void transpose_cast(const float* __restrict__ src,
                                                      u16* __restrict__ dst) {
  __shared__ float T[64][68];
  int tid = threadIdx.x;
  int n0 = blockIdx.x * 64, i0 = blockIdx.y * 64;
  size_t boff = (size_t)blockIdx.z << 20;
  const float* s = src + boff;
  u16* d = dst + boff;
  int ir = tid >> 4, n4 = (tid & 15) * 4;
#pragma unroll
  for (int r = 0; r < 4; ++r) {
    int i_loc = ir + r * 16;
    float4 v = *(const float4*)(s + (size_t)(i0 + i_loc) * 1024 + n0 + n4);
    *(float4*)&T[i_loc][n4] = v;
  }
  __syncthreads();
  int nr = tid >> 3, i8 = (tid & 7) * 8;
#pragma unroll
  for (int r = 0; r < 2; ++r) {
    int n_loc = nr + r * 32;
    u32 pk[4];
#pragma unroll
    for (int j = 0; j < 4; ++j) {
      float f0 = T[i8 + 2 * j][n_loc];
      float f1 = T[i8 + 2 * j + 1][n_loc];
      pk[j] = (u32)f2bf(f0) | ((u32)f2bf(f1) << 16);
    }
    *(uint4*)(d + (size_t)(n0 + n_loc) * 1024 + i0 + i8) = make_uint4(pk[0], pk[1], pk[2], pk[3]);
  }
}

// ---------------------------------------------------------------------------
// Cast weights to bf16. w=0..2: Wq/Wk/Wv as-is [o][i]. w=3: Wm' permuted so
// column c' = h*64+d maps to Wm column d*16+h (head-major K for final GEMM).
// grid (1024 rows, 4 weights), block 256 (4 cols/thread)
// ---------------------------------------------------------------------------
__global__ __launch_bounds__(256) void cast_weights(const float* __restrict__ Wq,
                                                    const float* __restrict__ Wk,
                                                    const float* __restrict__ Wv,
                                                    const float* __restrict__ Wm,
                                                    u16* __restrict__ out) {
  int w = blockIdx.y;
  const float* src = (w == 0) ? Wq : (w == 1) ? Wk : (w == 2) ? Wv : Wm;
  u16* dst = out + ((size_t)w << 20);
  int o = blockIdx.x;
  int c4 = threadIdx.x * 4;
  float f[4];
  if (w < 3) {
    float4 v = *(const float4*)(src + (size_t)o * 1024 + c4);
    f[0] = v.x; f[1] = v.y; f[2] = v.z; f[3] = v.w;
  } else {
#pragma unroll
    for (int j = 0; j < 4; ++j) {
      int cp = c4 + j;
      f[j] = src[(size_t)o * 1024 + (cp & 63) * 16 + (cp >> 6)];
    }
  }
  u32 p0 = (u32)f2bf(f[0]) | ((u32)f2bf(f[1]) << 16);
  u32 p1 = (u32)f2bf(f[2]) | ((u32)f2bf(f[3]) << 16);
  *(uint2*)(dst + (size_t)o * 1024 + c4) = make_uint2(p0, p1);
}

// ---------------------------------------------------------------------------
// bt-GEMM v2: C[c,n] = sum_k A[c,k] * B^T[n,k] (+bias). 128x128 tile, BK=64,
// 8 waves (4x2, wave tile 32x64), LDS double-buffer with issue-early staging
// (T3-min) and XOR-swizzled LDS (slot ^= row&7, pre-swizzled global source).
// BMODE 0: B^T = plain [b][n][k] (Xt).  BMODE 1: B^T[n][c'] from attention
//          output Xh[b][h][n][d] with c' = h*64+d (kt == h).
// OMODE 0: bf16 -> [b][h][n][d] (Q,K)   OMODE 1: bf16 -> [b][h][d][n] (V)
// OMODE 2: fp32 -> [b][c][n] (final out)
// grid (8 n-tiles, 8 c-tiles, 8 b), block 512
// ---------------------------------------------------------------------------
template <int BMODE, int OMODE>
__global__ __launch_bounds__(512) void gemm_bt(const u16* __restrict__ A,
                                               const u16* __restrict__ Bsrc,
                                               const float* __restrict__ bias,
                                               void* __restrict__ Out, float escale) {
  __shared__ u16 As[2][128 * 64];
  __shared__ u16 Bs[2][128 * 64];
  int tid = threadIdx.x;
  int wave = tid >> 6;
  int l = tid & 63, ln = l & 15, g = l >> 4;
  int n0 = blockIdx.x * 128, c0 = blockIdx.y * 128;
  size_t b = blockIdx.z;
  const u16* Bb = Bsrc + (b << 20);
  int wr = (wave >> 1) * 32, wc = (wave & 1) * 64;

  // staging: thread -> row tid>>3 (+0/64), swizzled 16B slot within the row
  int srow = tid >> 3;
  int sslot8 = ((tid & 7) ^ (srow & 7)) << 3;
  const u16* aS0 = A + (size_t)(c0 + srow) * 1024 + sslot8;
  const u16* aS1 = A + (size_t)(c0 + 64 + srow) * 1024 + sslot8;
  const u16* bS0;
  const u16* bS1;
  if (BMODE == 0) {
    bS0 = Bb + (size_t)(n0 + srow) * 1024 + sslot8;
    bS1 = Bb + (size_t)(n0 + 64 + srow) * 1024 + sslot8;
  } else {
    bS0 = Bb + (size_t)(n0 + srow) * 64 + sslot8;
    bS1 = Bb + (size_t)(n0 + 64 + srow) * 64 + sslot8;
  }
  int ldsbase = wave * 512;  // rows wave*8.. of each 64-row half

  f32x4 acc[2][4] = {};

#define STAGE(buf, kt)                                                        \
  do {                                                                        \
    int aofs = (kt)*64;                                                       \
    size_t bofs = (BMODE == 0) ? (size_t)(kt)*64 : ((size_t)(kt) << 16);      \
    gload_lds16(aS0 + aofs, &As[buf][ldsbase]);                               \
    gload_lds16(aS1 + aofs, &As[buf][ldsbase + 64 * 64]);                     \
    gload_lds16(bS0 + bofs, &Bs[buf][ldsbase]);                               \
    gload_lds16(bS1 + bofs, &Bs[buf][ldsbase + 64 * 64]);                     \
  } while (0)

  STAGE(0, 0);
  __syncthreads();
  int cur = 0;
  for (int kt = 0; kt < 16; ++kt) {
    if (kt < 15) STAGE(cur ^ 1, kt + 1);
    bf16x8 af[2][2], bfr[4][2];
#pragma unroll
    for (int m = 0; m < 2; ++m) {
      int r = wr + m * 16 + ln;
#pragma unroll
      for (int kk = 0; kk < 2; ++kk) {
        int s = ((kk * 4 + g) ^ (r & 7)) * 8;
        af[m][kk] = *(const bf16x8*)&As[cur][r * 64 + s];
      }
    }
#pragma unroll
    for (int n = 0; n < 4; ++n) {
      int r = wc + n * 16 + ln;
#pragma unroll
      for (int kk = 0; kk < 2; ++kk) {
        int s = ((kk * 4 + g) ^ (r & 7)) * 8;
        bfr[n][kk] = *(const bf16x8*)&Bs[cur][r * 64 + s];
      }
    }
#pragma unroll
    for (int kk = 0; kk < 2; ++kk)
#pragma unroll
      for (int m = 0; m < 2; ++m)
#pragma unroll
        for (int n = 0; n < 4; ++n)
          acc[m][n] = __builtin_amdgcn_mfma_f32_16x16x32_bf16(af[m][kk], bfr[n][kk], acc[m][n], 0, 0, 0);
    __syncthreads();
    cur ^= 1;
  }
#undef STAGE

#pragma unroll
  for (int m = 0; m < 2; ++m) {
#pragma unroll
    for (int r = 0; r < 4; ++r) {
      int c = c0 + wr + m * 16 + g * 4 + r;
      float bi = bias[c];
#pragma unroll
      for (int n = 0; n < 4; ++n) {
        int nn = n0 + wc + n * 16 + ln;
        float val = (acc[m][n][r] + bi) * escale;
        if (OMODE == 0)
          ((u16*)Out)[((b * 16 + (c & 15)) * 1024 + nn) * 64 + (c >> 4)] = f2bf(val);
        else if (OMODE == 1)
          ((u16*)Out)[((b * 16 + (c & 15)) * 64 + (c >> 4)) * 1024 + nn] = f2bf(val);
        else
          ((float*)Out)[(b << 20) + (size_t)c * 1024 + nn] = val;
      }
    }
  }
}

// ---------------------------------------------------------------------------
// Flash attention v2: one block = (b,h, 128 q-rows). No-max softmax (scores
// pre-scaled by log2e/8 in the Q projection; exp2 accumulated unnormalized,
// single divide at the end). K/V double-buffered via global_load_lds with
// pre-swizzled source (slot ^= row&7) + XOR-swizzled ds_reads. XCD-bijective
// block swizzle: all 8 blocks of one (b,h) land on one XCD consecutively.
// grid 1024 blocks x 256 threads.
// ---------------------------------------------------------------------------
__global__ __launch_bounds__(256) void attn_kernel(const u16* __restrict__ Qh,
                                                   const u16* __restrict__ Kh,
                                                   const u16* __restrict__ Vt,
                                                   u16* __restrict__ Xh) {
  __shared__ u16 Ks[2][4096];
  __shared__ u16 Vs[2][4096];
  __shared__ u16 Ps[8][16 * 72];  // [wave*2+tile][q-row][key], padded stride 72
  int tid = threadIdx.x;
  int w = tid >> 6, l = tid & 63, ln = l & 15, g = l >> 4;
  int id = blockIdx.x;
  int qp = (id & 63) >> 3;                 // q-pair index 0..7 (128 rows each)
  int bh = ((id >> 6) << 3) | (id & 7);    // xcd = id%8 = bh&7
  size_t hoff = (size_t)bh << 16;
  const u16* Qg = Qh + hoff;
  const u16* Kg = Kh + hoff;
  const u16* Vg = Vt + hoff;
  u16* Og = Xh + hoff;

  bf16x8 qf[2][2];
#pragma unroll
  for (int t = 0; t < 2; ++t)
#pragma unroll
    for (int kk = 0; kk < 2; ++kk)
      qf[t][kk] = *(const bf16x8*)(Qg + (size_t)(qp * 128 + t * 64 + w * 16 + ln) * 64 + kk * 32 + g * 8);

  // staging: wave w covers rows w*16 .. w*16+15 of the 64-row K/V tile
  int lr = l >> 3;                    // sub-row 0..7
  int sw8 = ((l & 7) ^ lr) << 3;      // swizzled 8-elem slot in source
  int r0 = w * 16 + lr, r1 = r0 + 8;
  const u16* kS0 = Kg + r0 * 64 + sw8;
  const u16* kS1 = Kg + r1 * 64 + sw8;
  const u16* vS0 = Vg + (size_t)r0 * 1024 + sw8;
  const u16* vS1 = Vg + (size_t)r1 * 1024 + sw8;

  f32x4 xacc[2][4] = {};
  float lacc[2] = {0.f, 0.f};

  gload_lds16(kS0, &Ks[0][(w * 2) * 512]);
  gload_lds16(kS1, &Ks[0][(w * 2 + 1) * 512]);
  gload_lds16(vS0, &Vs[0][(w * 2) * 512]);
  gload_lds16(vS1, &Vs[0][(w * 2 + 1) * 512]);
  __syncthreads();

  int sx = ln & 7;
  int cur = 0;
  for (int kt = 0; kt < 16; ++kt) {
    if (kt < 15) {
      int nxt = cur ^ 1;
      gload_lds16(kS0 + (kt + 1) * 4096, &Ks[nxt][(w * 2) * 512]);
      gload_lds16(kS1 + (kt + 1) * 4096, &Ks[nxt][(w * 2 + 1) * 512]);
      gload_lds16(vS0 + (kt + 1) * 64, &Vs[nxt][(w * 2) * 512]);
      gload_lds16(vS1 + (kt + 1) * 64, &Vs[nxt][(w * 2 + 1) * 512]);
    }
    bf16x8 kf[2][4], vf[2][4];
#pragma unroll
    for (int kk = 0; kk < 2; ++kk)
#pragma unroll
      for (int f = 0; f < 4; ++f) {
        int slot = (((kk << 2) + g) ^ sx) << 3;
        kf[kk][f] = *(const bf16x8*)&Ks[cur][(f * 16 + ln) * 64 + slot];
        vf[kk][f] = *(const bf16x8*)&Vs[cur][(f * 16 + ln) * 64 + slot];
      }
    f32x4 sacc[2][4] = {};
#pragma unroll
    for (int t = 0; t < 2; ++t)
#pragma unroll
      for (int kk = 0; kk < 2; ++kk)
#pragma unroll
        for (int f = 0; f < 4; ++f)
          sacc[t][f] = __builtin_amdgcn_mfma_f32_16x16x32_bf16(kf[kk][f], qf[t][kk], sacc[t][f], 0, 0, 0);
#pragma unroll
    for (int t = 0; t < 2; ++t) {
      u16* PsW = Ps[w * 2 + t];
#pragma unroll
      for (int f = 0; f < 4; ++f) {
        float p0 = __builtin_amdgcn_exp2f(sacc[t][f][0]);
        float p1 = __builtin_amdgcn_exp2f(sacc[t][f][1]);
        float p2 = __builtin_amdgcn_exp2f(sacc[t][f][2]);
        float p3 = __builtin_amdgcn_exp2f(sacc[t][f][3]);
        lacc[t] += (p0 + p1) + (p2 + p3);
        bf16x4 pb;
        pb[0] = (__bf16)p0; pb[1] = (__bf16)p1; pb[2] = (__bf16)p2; pb[3] = (__bf16)p3;
        *(bf16x4*)&PsW[ln * 72 + (f << 4) + (g << 2)] = pb;
      }
    }
#pragma unroll
    for (int t = 0; t < 2; ++t) {
      const u16* PsR = Ps[w * 2 + t];
#pragma unroll
      for (int kk = 0; kk < 2; ++kk) {
        bf16x8 pf = *(const bf16x8*)&PsR[ln * 72 + (kk << 5) + (g << 3)];
#pragma unroll
        for (int fd = 0; fd < 4; ++fd)
          xacc[t][fd] = __builtin_amdgcn_mfma_f32_16x16x32_bf16(pf, vf[kk][fd], xacc[t][fd], 0, 0, 0);
      }
    }
    __syncthreads();
    cur ^= 1;
  }

#pragma unroll
  for (int t = 0; t < 2; ++t) {
    float lt = lacc[t];
    lt += __shfl_xor(lt, 16);
    lt += __shfl_xor(lt, 32);
    float il[4];
#pragma unroll
    for (int r = 0; r < 4; ++r) il[r] = 1.0f / __shfl(lt, g * 4 + r);
#pragma unroll
    for (int fd = 0; fd < 4; ++fd)
#pragma unroll
      for (int r = 0; r < 4; ++r) {
        int nq = qp * 128 + t * 64 + w * 16 + g * 4 + r;
        Og[(size_t)nq * 64 + fd * 16 + ln] = f2bf(xacc[t][fd][r] * il[r]);
      }
  }
}

// ---------------------------------------------------------------------------
extern "C" void kernel_launch(void* const* d_in, const int* in_sizes, int n_in,
                              void* d_out, int out_size, void* d_ws, size_t ws_size,
                              hipStream_t stream) {
  const float* q  = (const float*)d_in[0];
  const float* k  = (const float*)d_in[1];
  const float* v  = (const float*)d_in[2];
  const float* Wq = (const float*)d_in[3];
  const float* bq = (const float*)d_in[4];
  const float* Wk = (const float*)d_in[5];
  const float* bk = (const float*)d_in[6];
  const float* Wv = (const float*)d_in[7];
  const float* bv = (const float*)d_in[8];
  const float* Wm = (const float*)d_in[9];
  const float* bm = (const float*)d_in[10];

  char* ws = (char*)d_ws;
  u16* Wbf = (u16*)ws;                      //  8 MB: Wq,Wk,Wv,Wm' bf16
  u16* Qh  = (u16*)(ws + (8ull << 20));     // 16 MB [b][h][n][d]
  u16* Kh  = (u16*)(ws + (24ull << 20));    // 16 MB [b][h][n][d]
  u16* Vt  = (u16*)(ws + (40ull << 20));    // 16 MB [b][h][d][n]
  u16* Xt  = (u16*)(ws + (56ull << 20));    // 16 MB, reused (Xt then Xh)

  cast_weights<<<dim3(1024, 4, 1), 256, 0, stream>>>(Wq, Wk, Wv, Wm, Wbf);

  dim3 tg(16, 16, 8), gg(8, 8, 8);

  // Q scale = 1/sqrt(64) * log2(e), folded so attention uses raw exp2
  const float qscale = 0.125f * 1.44269504088896340736f;

  transpose_cast<<<tg, 256, 0, stream>>>(q, Xt);
  gemm_bt<0, 0><<<gg, 512, 0, stream>>>(Wbf, Xt, bq, Qh, qscale);
  transpose_cast<<<tg, 256, 0, stream>>>(k, Xt);
  gemm_bt<0, 0><<<gg, 512, 0, stream>>>(Wbf + (1u << 20), Xt, bk, Kh, 1.0f);
  transpose_cast<<<tg, 256, 0, stream>>>(v, Xt);
  gemm_bt<0, 1><<<gg, 512, 0, stream>>>(Wbf + (2u << 20), Xt, bv, Vt, 1.0f);

  attn_kernel<<<1024, 256, 0, stream>>>(Qh, Kh, Vt, Xt);

  gemm_bt<1, 2><<<gg, 512, 0, stream>>>(Wbf + (3u << 20), Xt, bm, d_out, 1.0f);
}

// Round 5
// 217.318 us; speedup vs baseline: 1.2464x; 1.2464x over previous
//
#include <hip/hip_runtime.h>

typedef __bf16 bf16x8 __attribute__((ext_vector_type(8)));
typedef __bf16 bf16x4 __attribute__((ext_vector_type(4)));
typedef float f32x4 __attribute__((ext_vector_type(4)));
typedef unsigned short u16;
typedef unsigned int u32;

__device__ __forceinline__ u16 f2bf(float f) {
  u32 u = __builtin_bit_cast(u32, f);
  u = (u + 0x7FFFu + ((u >> 16) & 1u)) >> 16;
  return (u16)u;
}

__device__ __forceinline__ void gload_lds16(const void* g, void* l) {
  __builtin_amdgcn_global_load_lds((const __attribute__((address_space(1))) void*)g,
                                   (__attribute__((address_space(3))) void*)l, 16, 0, 0);
}

// ---------------------------------------------------------------------------
// Transpose + cast: src fp32 [b][1024 i][1024 n] -> dst bf16 [b][1024 n][1024 i]
// grid (16 n-tiles, 16 i-tiles, 8 b), block 256
// ---------------------------------------------------------------------------
__global__ __launch_bounds__(256) void transpose_cast(const float* __restrict__ src,
                                                      u16* __restrict__ dst) {
  __shared__ float T[64][68];
  int tid = threadIdx.x;
  int n0 = blockIdx.x * 64, i0 = blockIdx.y * 64;
  size_t boff = (size_t)blockIdx.z << 20;
  const float* s = src + boff;
  u16* d = dst + boff;
  int ir = tid >> 4, n4 = (tid & 15) * 4;
#pragma unroll
  for (int r = 0; r < 4; ++r) {
    int i_loc = ir + r * 16;
    float4 v = *(const float4*)(s + (size_t)(i0 + i_loc) * 1024 + n0 + n4);
    *(float4*)&T[i_loc][n4] = v;
  }
  __syncthreads();
  int nr = tid >> 3, i8 = (tid & 7) * 8;
#pragma unroll
  for (int r = 0; r < 2; ++r) {
    int n_loc = nr + r * 32;
    u32 pk[4];
#pragma unroll
    for (int j = 0; j < 4; ++j) {
      float f0 = T[i8 + 2 * j][n_loc];
      float f1 = T[i8 + 2 * j + 1][n_loc];
      pk[j] = (u32)f2bf(f0) | ((u32)f2bf(f1) << 16);
    }
    *(uint4*)(d + (size_t)(n0 + n_loc) * 1024 + i0 + i8) = make_uint4(pk[0], pk[1], pk[2], pk[3]);
  }
}

// ---------------------------------------------------------------------------
// Cast weights to bf16. w=0..2: Wq/Wk/Wv as-is [o][i]. w=3: Wm' permuted so
// column c' = h*64+d maps to Wm column d*16+h (head-major K for final GEMM).
// grid (1024 rows, 4 weights), block 256 (4 cols/thread)
// ---------------------------------------------------------------------------
__global__ __launch_bounds__(256) void cast_weights(const float* __restrict__ Wq,
                                                    const float* __restrict__ Wk,
                                                    const float* __restrict__ Wv,
                                                    const float* __restrict__ Wm,
                                                    u16* __restrict__ out) {
  int w = blockIdx.y;
  const float* src = (w == 0) ? Wq : (w == 1) ? Wk : (w == 2) ? Wv : Wm;
  u16* dst = out + ((size_t)w << 20);
  int o = blockIdx.x;
  int c4 = threadIdx.x * 4;
  float f[4];
  if (w < 3) {
    float4 v = *(const float4*)(src + (size_t)o * 1024 + c4);
    f[0] = v.x; f[1] = v.y; f[2] = v.z; f[3] = v.w;
  } else {
#pragma unroll
    for (int j = 0; j < 4; ++j) {
      int cp = c4 + j;
      f[j] = src[(size_t)o * 1024 + (cp & 63) * 16 + (cp >> 6)];
    }
  }
  u32 p0 = (u32)f2bf(f[0]) | ((u32)f2bf(f[1]) << 16);
  u32 p1 = (u32)f2bf(f[2]) | ((u32)f2bf(f[3]) << 16);
  *(uint2*)(dst + (size_t)o * 1024 + c4) = make_uint2(p0, p1);
}

// ---------------------------------------------------------------------------
// GEMM v3: C[c,ng] = sum_k A[c,k]*B[ng,k] (+bias)*escale. A = weight [1024x1024],
// B = 8192x1024 bf16 (k-contiguous rows). Tile 256(M)x128(N), BK=64, 8 waves
// as 4Mx2N (wave tile 64x64, 32 MFMA : 16 ds_read_b128). LDS double-buffered
// (96 KB), issue-early staging, XOR-swizzled slots (T2), XCD-chunked work
// remap (T1). grid 256 blocks x 512 threads (1 block/CU).
// EPI 0: bf16 -> Q/K layout [ng][h][d] (packed bf16x4 across d)
// EPI 1: bf16 -> V layout [b][h][d][n]
// EPI 2: fp32 -> [b][c][n]
// ---------------------------------------------------------------------------
template <int EPI>
__global__ __launch_bounds__(512) void gemm256(const u16* __restrict__ A,
                                               const u16* __restrict__ B,
                                               const float* __restrict__ bias,
                                               void* __restrict__ Out, float escale) {
  __shared__ u16 As[2][256 * 64];
  __shared__ u16 Bs[2][128 * 64];
  int tid = threadIdx.x;
  int wave = tid >> 6, l = tid & 63, ln = l & 15, g = l >> 4;
  int wm = wave >> 1, wn = wave & 1;
  int bid = blockIdx.x;
  int work = (bid & 7) * 32 + (bid >> 3);  // XCD-bijective remap (nwg=256)
  int mt = work >> 6, nt = work & 63;
  int c0 = mt * 256, n0 = nt * 128;

  int srow = tid >> 3;                       // 0..63
  int slot8 = ((tid & 7) ^ (srow & 7)) << 3; // pre-swizzled source slot
  const u16* aS = A + (size_t)(c0 + srow) * 1024 + slot8;
  const u16* bS = B + (size_t)(n0 + srow) * 1024 + slot8;
  int lbase = wave * 512;

  f32x4 acc[4][4] = {};

#define STAGE(buf, kt)                                                     \
  do {                                                                     \
    _Pragma("unroll") for (int i = 0; i < 4; ++i)                          \
        gload_lds16(aS + i * 65536 + (kt)*64, &As[buf][i * 4096 + lbase]); \
    _Pragma("unroll") for (int j = 0; j < 2; ++j)                          \
        gload_lds16(bS + j * 65536 + (kt)*64, &Bs[buf][j * 4096 + lbase]); \
  } while (0)

  STAGE(0, 0);
  __syncthreads();
  int cur = 0;
  for (int kt = 0; kt < 16; ++kt) {
    if (kt < 15) STAGE(cur ^ 1, kt + 1);
    bf16x8 af[4][2], bfr[4][2];
#pragma unroll
    for (int kk = 0; kk < 2; ++kk) {
      int s = ((kk * 4 + g) ^ (ln & 7)) << 3;
#pragma unroll
      for (int mm = 0; mm < 4; ++mm)
        af[mm][kk] = *(const bf16x8*)&As[cur][(wm * 64 + mm * 16 + ln) * 64 + s];
#pragma unroll
      for (int nn = 0; nn < 4; ++nn)
        bfr[nn][kk] = *(const bf16x8*)&Bs[cur][(wn * 64 + nn * 16 + ln) * 64 + s];
    }
#pragma unroll
    for (int kk = 0; kk < 2; ++kk)
#pragma unroll
      for (int mm = 0; mm < 4; ++mm)
#pragma unroll
        for (int nn = 0; nn < 4; ++nn)
          acc[mm][nn] = __builtin_amdgcn_mfma_f32_16x16x32_bf16(af[mm][kk], bfr[nn][kk], acc[mm][nn], 0, 0, 0);
    __syncthreads();
    cur ^= 1;
  }
#undef STAGE

  int D0 = (c0 >> 4) + wm * 4;
#pragma unroll
  for (int nn = 0; nn < 4; ++nn) {
    size_t ng = (size_t)n0 + wn * 64 + nn * 16 + ln;
#pragma unroll
    for (int r = 0; r < 4; ++r) {
      int h = g * 4 + r;
      if (EPI == 0) {
        bf16x4 pk;
#pragma unroll
        for (int mm = 0; mm < 4; ++mm) {
          int c = c0 + wm * 64 + mm * 16 + h;
          pk[mm] = (__bf16)((acc[mm][nn][r] + bias[c]) * escale);
        }
        *(bf16x4*)((u16*)Out + ng * 1024 + (size_t)h * 64 + D0) = pk;
      } else {
        size_t b = ng >> 10, n = ng & 1023;
#pragma unroll
        for (int mm = 0; mm < 4; ++mm) {
          int c = c0 + wm * 64 + mm * 16 + h;
          float val = (acc[mm][nn][r] + bias[c]) * escale;
          if (EPI == 1) {
            int d = D0 + mm;
            ((u16*)Out)[((b * 16 + h) * 64 + d) * 1024 + n] = f2bf(val);
          } else {
            ((float*)Out)[(b << 20) + (size_t)c * 1024 + n] = val;
          }
        }
      }
    }
  }
}

// ---------------------------------------------------------------------------
// Flash attention: one block = (b,h, 128 q-rows). Q,K in [b][n][h][d]
// (row stride 1024), V in [b][h][d][n]. No-max softmax (exp2, scale folded
// into Q), K/V double-buffered via swizzled global_load_lds. Output Xh in
// [b][n][h*64+d] (flat 8192x1024 for the final GEMM).
// grid 1024 blocks x 256 threads, XCD-grouped by (b,h).
// ---------------------------------------------------------------------------
__global__ __launch_bounds__(256) void attn_kernel(const u16* __restrict__ Qh,
                                                   const u16* __restrict__ Kh,
                                                   const u16* __restrict__ Vt,
                                                   u16* __restrict__ Xh) {
  __shared__ u16 Ks[2][4096];
  __shared__ u16 Vs[2][4096];
  __shared__ u16 Ps[8][16 * 72];
  int tid = threadIdx.x;
  int w = tid >> 6, l = tid & 63, ln = l & 15, g = l >> 4;
  int id = blockIdx.x;
  int qp = (id & 63) >> 3;
  int bh = ((id >> 6) << 3) | (id & 7);  // xcd = id%8 = bh&7
  size_t b = bh >> 4;
  int h = bh & 15;
  const u16* Qg = Qh + (b << 20) + (h << 6);
  const u16* Kg = Kh + (b << 20) + (h << 6);
  const u16* Vg = Vt + ((size_t)bh << 16);
  u16* Og = Xh + (b << 20) + (h << 6);

  bf16x8 qf[2][2];
#pragma unroll
  for (int t = 0; t < 2; ++t)
#pragma unroll
    for (int kk = 0; kk < 2; ++kk)
      qf[t][kk] = *(const bf16x8*)(Qg + (size_t)(qp * 128 + t * 64 + w * 16 + ln) * 1024 + kk * 32 + g * 8);

  int lr = l >> 3;
  int sw8 = ((l & 7) ^ lr) << 3;
  int r0 = w * 16 + lr, r1 = r0 + 8;
  const u16* kS0 = Kg + (size_t)r0 * 1024 + sw8;
  const u16* kS1 = Kg + (size_t)r1 * 1024 + sw8;
  const u16* vS0 = Vg + (size_t)r0 * 1024 + sw8;
  const u16* vS1 = Vg + (size_t)r1 * 1024 + sw8;

  f32x4 xacc[2][4] = {};
  float lacc[2] = {0.f, 0.f};

  gload_lds16(kS0, &Ks[0][(w * 2) * 512]);
  gload_lds16(kS1, &Ks[0][(w * 2 + 1) * 512]);
  gload_lds16(vS0, &Vs[0][(w * 2) * 512]);
  gload_lds16(vS1, &Vs[0][(w * 2 + 1) * 512]);
  __syncthreads();

  int sx = ln & 7;
  int cur = 0;
  for (int kt = 0; kt < 16; ++kt) {
    if (kt < 15) {
      int nxt = cur ^ 1;
      gload_lds16(kS0 + (size_t)(kt + 1) * 65536, &Ks[nxt][(w * 2) * 512]);
      gload_lds16(kS1 + (size_t)(kt + 1) * 65536, &Ks[nxt][(w * 2 + 1) * 512]);
      gload_lds16(vS0 + (kt + 1) * 64, &Vs[nxt][(w * 2) * 512]);
      gload_lds16(vS1 + (kt + 1) * 64, &Vs[nxt][(w * 2 + 1) * 512]);
    }
    bf16x8 kf[2][4], vf[2][4];
#pragma unroll
    for (int kk = 0; kk < 2; ++kk)
#pragma unroll
      for (int f = 0; f < 4; ++f) {
        int slot = (((kk << 2) + g) ^ sx) << 3;
        kf[kk][f] = *(const bf16x8*)&Ks[cur][(f * 16 + ln) * 64 + slot];
        vf[kk][f] = *(const bf16x8*)&Vs[cur][(f * 16 + ln) * 64 + slot];
      }
    f32x4 sacc[2][4] = {};
#pragma unroll
    for (int t = 0; t < 2; ++t)
#pragma unroll
      for (int kk = 0; kk < 2; ++kk)
#pragma unroll
        for (int f = 0; f < 4; ++f)
          sacc[t][f] = __builtin_amdgcn_mfma_f32_16x16x32_bf16(kf[kk][f], qf[t][kk], sacc[t][f], 0, 0, 0);
#pragma unroll
    for (int t = 0; t < 2; ++t) {
      u16* PsW = Ps[w * 2 + t];
#pragma unroll
      for (int f = 0; f < 4; ++f) {
        float p0 = __builtin_amdgcn_exp2f(sacc[t][f][0]);
        float p1 = __builtin_amdgcn_exp2f(sacc[t][f][1]);
        float p2 = __builtin_amdgcn_exp2f(sacc[t][f][2]);
        float p3 = __builtin_amdgcn_exp2f(sacc[t][f][3]);
        lacc[t] += (p0 + p1) + (p2 + p3);
        bf16x4 pb;
        pb[0] = (__bf16)p0; pb[1] = (__bf16)p1; pb[2] = (__bf16)p2; pb[3] = (__bf16)p3;
        *(bf16x4*)&PsW[ln * 72 + (f << 4) + (g << 2)] = pb;
      }
    }
#pragma unroll
    for (int t = 0; t < 2; ++t) {
      const u16* PsR = Ps[w * 2 + t];
#pragma unroll
      for (int kk = 0; kk < 2; ++kk) {
        bf16x8 pf = *(const bf16x8*)&PsR[ln * 72 + (kk << 5) + (g << 3)];
#pragma unroll
        for (int fd = 0; fd < 4; ++fd)
          xacc[t][fd] = __builtin_amdgcn_mfma_f32_16x16x32_bf16(pf, vf[kk][fd], xacc[t][fd], 0, 0, 0);
      }
    }
    __syncthreads();
    cur ^= 1;
  }

#pragma unroll
  for (int t = 0; t < 2; ++t) {
    float lt = lacc[t];
    lt += __shfl_xor(lt, 16);
    lt += __shfl_xor(lt, 32);
    float il[4];
#pragma unroll
    for (int r = 0; r < 4; ++r) il[r] = 1.0f / __shfl(lt, g * 4 + r);
#pragma unroll
    for (int fd = 0; fd < 4; ++fd)
#pragma unroll
      for (int r = 0; r < 4; ++r) {
        int nq = qp * 128 + t * 64 + w * 16 + g * 4 + r;
        Og[(size_t)nq * 1024 + fd * 16 + ln] = f2bf(xacc[t][fd][r] * il[r]);
      }
  }
}

// ---------------------------------------------------------------------------
extern "C" void kernel_launch(void* const* d_in, const int* in_sizes, int n_in,
                              void* d_out, int out_size, void* d_ws, size_t ws_size,
                              hipStream_t stream) {
  const float* q  = (const float*)d_in[0];
  const float* k  = (const float*)d_in[1];
  const float* v  = (const float*)d_in[2];
  const float* Wq = (const float*)d_in[3];
  const float* bq = (const float*)d_in[4];
  const float* Wk = (const float*)d_in[5];
  const float* bk = (const float*)d_in[6];
  const float* Wv = (const float*)d_in[7];
  const float* bv = (const float*)d_in[8];
  const float* Wm = (const float*)d_in[9];
  const float* bm = (const float*)d_in[10];

  char* ws = (char*)d_ws;
  u16* Wbf = (u16*)ws;                      //  8 MB: Wq,Wk,Wv,Wm' bf16
  u16* Qh  = (u16*)(ws + (8ull << 20));     // 16 MB [b][n][h][d]
  u16* Kh  = (u16*)(ws + (24ull << 20));    // 16 MB [b][n][h][d]
  u16* Vt  = (u16*)(ws + (40ull << 20));    // 16 MB [b][h][d][n]
  u16* Xt  = (u16*)(ws + (56ull << 20));    // 16 MB, reused (X^T, then attn out)

  cast_weights<<<dim3(1024, 4, 1), 256, 0, stream>>>(Wq, Wk, Wv, Wm, Wbf);

  dim3 tg(16, 16, 8);
  const float qscale = 0.125f * 1.44269504088896340736f;  // 1/sqrt(64) * log2(e)

  transpose_cast<<<tg, 256, 0, stream>>>(q, Xt);
  gemm256<0><<<256, 512, 0, stream>>>(Wbf, Xt, bq, Qh, qscale);
  transpose_cast<<<tg, 256, 0, stream>>>(k, Xt);
  gemm256<0><<<256, 512, 0, stream>>>(Wbf + (1u << 20), Xt, bk, Kh, 1.0f);
  transpose_cast<<<tg, 256, 0, stream>>>(v, Xt);
  gemm256<1><<<256, 512, 0, stream>>>(Wbf + (2u << 20), Xt, bv, Vt, 1.0f);

  attn_kernel<<<1024, 256, 0, stream>>>(Qh, Kh, Vt, Xt);

  gemm256<2><<<256, 512, 0, stream>>>(Wbf + (3u << 20), Xt, bm, d_out, 1.0f);
}

// Round 6
// 199.707 us; speedup vs baseline: 1.3563x; 1.0882x over previous
//
#include <hip/hip_runtime.h>

typedef __bf16 bf16x8 __attribute__((ext_vector_type(8)));
typedef __bf16 bf16x4 __attribute__((ext_vector_type(4)));
typedef float f32x4 __attribute__((ext_vector_type(4)));
typedef unsigned short u16;
typedef unsigned int u32;

__device__ __forceinline__ u16 f2bf(float f) {
  u32 u = __builtin_bit_cast(u32, f);
  u = (u + 0x7FFFu + ((u >> 16) & 1u)) >> 16;
  return (u16)u;
}

__device__ __forceinline__ void gload_lds16(const void* g, void* l) {
  __builtin_amdgcn_global_load_lds((const __attribute__((address_space(1))) void*)g,
                                   (__attribute__((address_space(3))) void*)l, 16, 0, 0);
}

// ---------------------------------------------------------------------------
// Transpose + cast: src fp32 [b][1024 i][1024 n] -> dst bf16 [b][1024 n][1024 i]
// ---------------------------------------------------------------------------
__global__ __launch_bounds__(256) void transpose_cast(const float* __restrict__ src,
                                                      u16* __restrict__ dst) {
  __shared__ float T[64][68];
  int tid = threadIdx.x;
  int n0 = blockIdx.x * 64, i0 = blockIdx.y * 64;
  size_t boff = (size_t)blockIdx.z << 20;
  const float* s = src + boff;
  u16* d = dst + boff;
  int ir = tid >> 4, n4 = (tid & 15) * 4;
#pragma unroll
  for (int r = 0; r < 4; ++r) {
    int i_loc = ir + r * 16;
    float4 v = *(const float4*)(s + (size_t)(i0 + i_loc) * 1024 + n0 + n4);
    *(float4*)&T[i_loc][n4] = v;
  }
  __syncthreads();
  int nr = tid >> 3, i8 = (tid & 7) * 8;
#pragma unroll
  for (int r = 0; r < 2; ++r) {
    int n_loc = nr + r * 32;
    u32 pk[4];
#pragma unroll
    for (int j = 0; j < 4; ++j) {
      float f0 = T[i8 + 2 * j][n_loc];
      float f1 = T[i8 + 2 * j + 1][n_loc];
      pk[j] = (u32)f2bf(f0) | ((u32)f2bf(f1) << 16);
    }
    *(uint4*)(d + (size_t)(n0 + n_loc) * 1024 + i0 + i8) = make_uint4(pk[0], pk[1], pk[2], pk[3]);
  }
}

// ---------------------------------------------------------------------------
// Cast weights to bf16. w=0..2: Wq/Wk/Wv as-is. w=3: Wm' column-permuted.
// ---------------------------------------------------------------------------
__global__ __launch_bounds__(256) void cast_weights(const float* __restrict__ Wq,
                                                    const float* __restrict__ Wk,
                                                    const float* __restrict__ Wv,
                                                    const float* __restrict__ Wm,
                                                    u16* __restrict__ out) {
  int w = blockIdx.y;
  const float* src = (w == 0) ? Wq : (w == 1) ? Wk : (w == 2) ? Wv : Wm;
  u16* dst = out + ((size_t)w << 20);
  int o = blockIdx.x;
  int c4 = threadIdx.x * 4;
  float f[4];
  if (w < 3) {
    float4 v = *(const float4*)(src + (size_t)o * 1024 + c4);
    f[0] = v.x; f[1] = v.y; f[2] = v.z; f[3] = v.w;
  } else {
#pragma unroll
    for (int j = 0; j < 4; ++j) {
      int cp = c4 + j;
      f[j] = src[(size_t)o * 1024 + (cp & 63) * 16 + (cp >> 6)];
    }
  }
  u32 p0 = (u32)f2bf(f[0]) | ((u32)f2bf(f[1]) << 16);
  u32 p1 = (u32)f2bf(f[2]) | ((u32)f2bf(f[3]) << 16);
  *(uint2*)(dst + (size_t)o * 1024 + c4) = make_uint2(p0, p1);
}

// ---------------------------------------------------------------------------
// GEMM v4 (counted-vmcnt pipeline): C[c,ng] = sum_k A[c,k]*B[ng,k] (+bias).
// BM=128, BN=256, BK=32, 8 waves (2M x 4N, wave-tile 64x64). Triple-buffered
// LDS (72 KB), 2-deep prefetch, s_waitcnt vmcnt(6) (never 0 mid-loop), raw
// s_barrier pairs. Pair-row XOR swizzle: LDS row (128B) = 2 global rows; slot
// sl = ((row&1)*4+g) ^ ((row>>1)&7), pre-swizzled global source (rule #21).
// XCD remap: xcd = bid&7 owns nt in [4*xcd, 4*xcd+4) for all mt.
// EPI 0: bf16 -> Q/K [ng][h][d]  EPI 1: bf16 -> V [b][h][d][n]
// EPI 2: fp32 -> [b][c][n]
// grid 256 x 512 threads, 2 blocks/CU.
// ---------------------------------------------------------------------------
template <int EPI>
__global__ __launch_bounds__(512, 4) void gemm8p(const u16* __restrict__ A,
                                                 const u16* __restrict__ B,
                                                 const float* __restrict__ bias,
                                                 void* __restrict__ Out, float escale) {
  // u16 offsets: A bufs at b*4096 (8KB each), B bufs at 12288 + b*8192 (16KB)
  __shared__ u16 LD[36864];  // 72 KB
  int tid = threadIdx.x;
  int wave = tid >> 6, l = tid & 63, ln = l & 15, g = l >> 4;
  int wm = wave >> 2, wn = wave & 3;
  int bid = blockIdx.x;
  int mt = (bid >> 3) & 7;
  int nt = ((bid & 7) << 2) | (bid >> 6);
  int c0 = mt * 128, n0 = nt * 256;

  // staging source (pre-swizzled): thread i covers LDS 16B-slot i of the chunk
  int R = tid >> 3, sl = tid & 7;
  int v = sl ^ (R & 7);
  int sa = v >> 2, sg = v & 3;
  const u16* aSrc = A + (size_t)(c0 + 2 * R + sa) * 1024 + sg * 8;
  const u16* bSrc0 = B + (size_t)(n0 + 2 * R + sa) * 1024 + sg * 8;
  const u16* bSrc1 = B + (size_t)(n0 + 128 + 2 * R + sa) * 1024 + sg * 8;

  // fragment read offsets (u16 units): row X -> LDSrow X>>1 (64 u16 each),
  // slot ((X&1)*4+g) ^ ((X>>1)&7). For X = base + mm*16 + ln the slot is
  // mm-independent: slr = (((ln&1)<<2)|g) ^ ((ln>>1)&7).
  int slr = ((((ln & 1) << 2) | g) ^ ((ln >> 1) & 7)) * 8;
  int laneA = (wm * 32 + (ln >> 1)) * 64 + slr;
  int laneB = (wn * 32 + (ln >> 1)) * 64 + slr;

  f32x4 acc[4][4] = {};

#define STAGE(buf, kt)                                                  \
  do {                                                                  \
    gload_lds16(aSrc + (kt) * 32, &LD[(buf) * 4096 + tid * 8]);         \
    gload_lds16(bSrc0 + (kt) * 32, &LD[12288 + (buf) * 8192 + tid * 8]);\
    gload_lds16(bSrc1 + (kt) * 32,                                      \
                &LD[12288 + (buf) * 8192 + 4096 + tid * 8]);            \
  } while (0)

  STAGE(0, 0);
  STAGE(1, 1);
  asm volatile("s_waitcnt vmcnt(3)" ::: "memory");
  asm volatile("s_barrier" ::: "memory");

#pragma unroll
  for (int t = 0; t < 32; ++t) {
    if (t < 30) {
      STAGE((t + 2) % 3, t + 2);
      asm volatile("s_waitcnt vmcnt(6)" ::: "memory");
    } else if (t == 30) {
      asm volatile("s_waitcnt vmcnt(3)" ::: "memory");
    } else {
      asm volatile("s_waitcnt vmcnt(0)" ::: "memory");
    }
    asm volatile("s_barrier" ::: "memory");
    const int ab = (t % 3) * 4096;
    const int bb = 12288 + (t % 3) * 8192;
    bf16x8 af[4], bfr[4];
#pragma unroll
    for (int mm = 0; mm < 4; ++mm) af[mm] = *(const bf16x8*)&LD[ab + laneA + mm * 512];
#pragma unroll
    for (int nn = 0; nn < 4; ++nn) bfr[nn] = *(const bf16x8*)&LD[bb + laneB + nn * 512];
    __builtin_amdgcn_s_setprio(1);
#pragma unroll
    for (int mm = 0; mm < 4; ++mm)
#pragma unroll
      for (int nn = 0; nn < 4; ++nn)
        acc[mm][nn] = __builtin_amdgcn_mfma_f32_16x16x32_bf16(af[mm], bfr[nn], acc[mm][nn], 0, 0, 0);
    __builtin_amdgcn_s_setprio(0);
    asm volatile("s_barrier" ::: "memory");
  }
#undef STAGE

  int D0 = (c0 >> 4) + wm * 4;
#pragma unroll
  for (int nn = 0; nn < 4; ++nn) {
    size_t ng = (size_t)n0 + wn * 64 + nn * 16 + ln;
#pragma unroll
    for (int r = 0; r < 4; ++r) {
      int h = g * 4 + r;
      if (EPI == 0) {
        bf16x4 pk;
#pragma unroll
        for (int mm = 0; mm < 4; ++mm) {
          int c = c0 + wm * 64 + mm * 16 + h;
          pk[mm] = (__bf16)((acc[mm][nn][r] + bias[c]) * escale);
        }
        *(bf16x4*)((u16*)Out + ng * 1024 + (size_t)h * 64 + D0) = pk;
      } else {
        size_t b = ng >> 10, n = ng & 1023;
#pragma unroll
        for (int mm = 0; mm < 4; ++mm) {
          int c = c0 + wm * 64 + mm * 16 + h;
          float val = (acc[mm][nn][r] + bias[c]) * escale;
          if (EPI == 1) {
            int d = D0 + mm;
            ((u16*)Out)[((b * 16 + h) * 64 + d) * 1024 + n] = f2bf(val);
          } else {
            ((float*)Out)[(b << 20) + (size_t)c * 1024 + n] = val;
          }
        }
      }
    }
  }
}

// ---------------------------------------------------------------------------
// Flash attention (unchanged from r5): one block = (b,h, 128 q-rows).
// Q,K in [b][n][h][d], V in [b][h][d][n]. No-max exp2 softmax, K/V
// double-buffered via swizzled global_load_lds. Output [b][n][h*64+d].
// ---------------------------------------------------------------------------
__global__ __launch_bounds__(256) void attn_kernel(const u16* __restrict__ Qh,
                                                   const u16* __restrict__ Kh,
                                                   const u16* __restrict__ Vt,
                                                   u16* __restrict__ Xh) {
  __shared__ u16 Ks[2][4096];
  __shared__ u16 Vs[2][4096];
  __shared__ u16 Ps[8][16 * 72];
  int tid = threadIdx.x;
  int w = tid >> 6, l = tid & 63, ln = l & 15, g = l >> 4;
  int id = blockIdx.x;
  int qp = (id & 63) >> 3;
  int bh = ((id >> 6) << 3) | (id & 7);
  size_t b = bh >> 4;
  int h = bh & 15;
  const u16* Qg = Qh + (b << 20) + (h << 6);
  const u16* Kg = Kh + (b << 20) + (h << 6);
  const u16* Vg = Vt + ((size_t)bh << 16);
  u16* Og = Xh + (b << 20) + (h << 6);

  bf16x8 qf[2][2];
#pragma unroll
  for (int t = 0; t < 2; ++t)
#pragma unroll
    for (int kk = 0; kk < 2; ++kk)
      qf[t][kk] = *(const bf16x8*)(Qg + (size_t)(qp * 128 + t * 64 + w * 16 + ln) * 1024 + kk * 32 + g * 8);

  int lr = l >> 3;
  int sw8 = ((l & 7) ^ lr) << 3;
  int r0 = w * 16 + lr, r1 = r0 + 8;
  const u16* kS0 = Kg + (size_t)r0 * 1024 + sw8;
  const u16* kS1 = Kg + (size_t)r1 * 1024 + sw8;
  const u16* vS0 = Vg + (size_t)r0 * 1024 + sw8;
  const u16* vS1 = Vg + (size_t)r1 * 1024 + sw8;

  f32x4 xacc[2][4] = {};
  float lacc[2] = {0.f, 0.f};

  gload_lds16(kS0, &Ks[0][(w * 2) * 512]);
  gload_lds16(kS1, &Ks[0][(w * 2 + 1) * 512]);
  gload_lds16(vS0, &Vs[0][(w * 2) * 512]);
  gload_lds16(vS1, &Vs[0][(w * 2 + 1) * 512]);
  __syncthreads();

  int sx = ln & 7;
  int cur = 0;
  for (int kt = 0; kt < 16; ++kt) {
    if (kt < 15) {
      int nxt = cur ^ 1;
      gload_lds16(kS0 + (size_t)(kt + 1) * 65536, &Ks[nxt][(w * 2) * 512]);
      gload_lds16(kS1 + (size_t)(kt + 1) * 65536, &Ks[nxt][(w * 2 + 1) * 512]);
      gload_lds16(vS0 + (kt + 1) * 64, &Vs[nxt][(w * 2) * 512]);
      gload_lds16(vS1 + (kt + 1) * 64, &Vs[nxt][(w * 2 + 1) * 512]);
    }
    bf16x8 kf[2][4], vf[2][4];
#pragma unroll
    for (int kk = 0; kk < 2; ++kk)
#pragma unroll
      for (int f = 0; f < 4; ++f) {
        int slot = (((kk << 2) + g) ^ sx) << 3;
        kf[kk][f] = *(const bf16x8*)&Ks[cur][(f * 16 + ln) * 64 + slot];
        vf[kk][f] = *(const bf16x8*)&Vs[cur][(f * 16 + ln) * 64 + slot];
      }
    f32x4 sacc[2][4] = {};
#pragma unroll
    for (int t = 0; t < 2; ++t)
#pragma unroll
      for (int kk = 0; kk < 2; ++kk)
#pragma unroll
        for (int f = 0; f < 4; ++f)
          sacc[t][f] = __builtin_amdgcn_mfma_f32_16x16x32_bf16(kf[kk][f], qf[t][kk], sacc[t][f], 0, 0, 0);
#pragma unroll
    for (int t = 0; t < 2; ++t) {
      u16* PsW = Ps[w * 2 + t];
#pragma unroll
      for (int f = 0; f < 4; ++f) {
        float p0 = __builtin_amdgcn_exp2f(sacc[t][f][0]);
        float p1 = __builtin_amdgcn_exp2f(sacc[t][f][1]);
        float p2 = __builtin_amdgcn_exp2f(sacc[t][f][2]);
        float p3 = __builtin_amdgcn_exp2f(sacc[t][f][3]);
        lacc[t] += (p0 + p1) + (p2 + p3);
        bf16x4 pb;
        pb[0] = (__bf16)p0; pb[1] = (__bf16)p1; pb[2] = (__bf16)p2; pb[3] = (__bf16)p3;
        *(bf16x4*)&PsW[ln * 72 + (f << 4) + (g << 2)] = pb;
      }
    }
#pragma unroll
    for (int t = 0; t < 2; ++t) {
      const u16* PsR = Ps[w * 2 + t];
#pragma unroll
      for (int kk = 0; kk < 2; ++kk) {
        bf16x8 pf = *(const bf16x8*)&PsR[ln * 72 + (kk << 5) + (g << 3)];
#pragma unroll
        for (int fd = 0; fd < 4; ++fd)
          xacc[t][fd] = __builtin_amdgcn_mfma_f32_16x16x32_bf16(pf, vf[kk][fd], xacc[t][fd], 0, 0, 0);
      }
    }
    __syncthreads();
    cur ^= 1;
  }

#pragma unroll
  for (int t = 0; t < 2; ++t) {
    float lt = lacc[t];
    lt += __shfl_xor(lt, 16);
    lt += __shfl_xor(lt, 32);
    float il[4];
#pragma unroll
    for (int r = 0; r < 4; ++r) il[r] = 1.0f / __shfl(lt, g * 4 + r);
#pragma unroll
    for (int fd = 0; fd < 4; ++fd)
#pragma unroll
      for (int r = 0; r < 4; ++r) {
        int nq = qp * 128 + t * 64 + w * 16 + g * 4 + r;
        Og[(size_t)nq * 1024 + fd * 16 + ln] = f2bf(xacc[t][fd][r] * il[r]);
      }
  }
}

// ---------------------------------------------------------------------------
extern "C" void kernel_launch(void* const* d_in, const int* in_sizes, int n_in,
                              void* d_out, int out_size, void* d_ws, size_t ws_size,
                              hipStream_t stream) {
  const float* q  = (const float*)d_in[0];
  const float* k  = (const float*)d_in[1];
  const float* v  = (const float*)d_in[2];
  const float* Wq = (const float*)d_in[3];
  const float* bq = (const float*)d_in[4];
  const float* Wk = (const float*)d_in[5];
  const float* bk = (const float*)d_in[6];
  const float* Wv = (const float*)d_in[7];
  const float* bv = (const float*)d_in[8];
  const float* Wm = (const float*)d_in[9];
  const float* bm = (const float*)d_in[10];

  char* ws = (char*)d_ws;
  u16* Wbf = (u16*)ws;                      //  8 MB: Wq,Wk,Wv,Wm' bf16
  u16* Qh  = (u16*)(ws + (8ull << 20));     // 16 MB [b][n][h][d]
  u16* Kh  = (u16*)(ws + (24ull << 20));    // 16 MB [b][n][h][d]
  u16* Vt  = (u16*)(ws + (40ull << 20));    // 16 MB [b][h][d][n]
  u16* Xt  = (u16*)(ws + (56ull << 20));    // 16 MB, reused (X^T, then attn out)

  cast_weights<<<dim3(1024, 4, 1), 256, 0, stream>>>(Wq, Wk, Wv, Wm, Wbf);

  dim3 tg(16, 16, 8);
  const float qscale = 0.125f * 1.44269504088896340736f;  // 1/sqrt(64) * log2(e)

  transpose_cast<<<tg, 256, 0, stream>>>(q, Xt);
  gemm8p<0><<<256, 512, 0, stream>>>(Wbf, Xt, bq, Qh, qscale);
  transpose_cast<<<tg, 256, 0, stream>>>(k, Xt);
  gemm8p<0><<<256, 512, 0, stream>>>(Wbf + (1u << 20), Xt, bk, Kh, 1.0f);
  transpose_cast<<<tg, 256, 0, stream>>>(v, Xt);
  gemm8p<1><<<256, 512, 0, stream>>>(Wbf + (2u << 20), Xt, bv, Vt, 1.0f);

  attn_kernel<<<1024, 256, 0, stream>>>(Qh, Kh, Vt, Xt);

  gemm8p<2><<<256, 512, 0, stream>>>(Wbf + (3u << 20), Xt, bm, d_out, 1.0f);
}

// Round 8
// 190.636 us; speedup vs baseline: 1.4208x; 1.0476x over previous
//
#include <hip/hip_runtime.h>

typedef __bf16 bf16x8 __attribute__((ext_vector_type(8)));
typedef __bf16 bf16x4 __attribute__((ext_vector_type(4)));
typedef float f32x4 __attribute__((ext_vector_type(4)));
typedef unsigned short u16;
typedef unsigned int u32;

__device__ __forceinline__ u16 f2bf(float f) {
  u32 u = __builtin_bit_cast(u32, f);
  u = (u + 0x7FFFu + ((u >> 16) & 1u)) >> 16;
  return (u16)u;
}

__device__ __forceinline__ void gload_lds16(const void* g, void* l) {
  __builtin_amdgcn_global_load_lds((const __attribute__((address_space(1))) void*)g,
                                   (__attribute__((address_space(3))) void*)l, 16, 0, 0);
}

// ---------------------------------------------------------------------------
// Transpose + cast: src fp32 [b][1024 i][1024 n] -> dst bf16 [b][1024 n][1024 i]
// ---------------------------------------------------------------------------
__global__ __launch_bounds__(256) void transpose_cast(const float* __restrict__ src,
                                                      u16* __restrict__ dst) {
  __shared__ float T[64][68];
  int tid = threadIdx.x;
  int n0 = blockIdx.x * 64, i0 = blockIdx.y * 64;
  size_t boff = (size_t)blockIdx.z << 20;
  const float* s = src + boff;
  u16* d = dst + boff;
  int ir = tid >> 4, n4 = (tid & 15) * 4;
#pragma unroll
  for (int r = 0; r < 4; ++r) {
    int i_loc = ir + r * 16;
    float4 v = *(const float4*)(s + (size_t)(i0 + i_loc) * 1024 + n0 + n4);
    *(float4*)&T[i_loc][n4] = v;
  }
  __syncthreads();
  int nr = tid >> 3, i8 = (tid & 7) * 8;
#pragma unroll
  for (int r = 0; r < 2; ++r) {
    int n_loc = nr + r * 32;
    u32 pk[4];
#pragma unroll
    for (int j = 0; j < 4; ++j) {
      float f0 = T[i8 + 2 * j][n_loc];
      float f1 = T[i8 + 2 * j + 1][n_loc];
      pk[j] = (u32)f2bf(f0) | ((u32)f2bf(f1) << 16);
    }
    *(uint4*)(d + (size_t)(n0 + n_loc) * 1024 + i0 + i8) = make_uint4(pk[0], pk[1], pk[2], pk[3]);
  }
}

// ---------------------------------------------------------------------------
// Cast weights to bf16. w=0..2: Wq/Wk/Wv as-is. w=3: Wm' column-permuted.
// ---------------------------------------------------------------------------
__global__ __launch_bounds__(256) void cast_weights(const float* __restrict__ Wq,
                                                    const float* __restrict__ Wk,
                                                    const float* __restrict__ Wv,
                                                    const float* __restrict__ Wm,
                                                    u16* __restrict__ out) {
  int w = blockIdx.y;
  const float* src = (w == 0) ? Wq : (w == 1) ? Wk : (w == 2) ? Wv : Wm;
  u16* dst = out + ((size_t)w << 20);
  int o = blockIdx.x;
  int c4 = threadIdx.x * 4;
  float f[4];
  if (w < 3) {
    float4 v = *(const float4*)(src + (size_t)o * 1024 + c4);
    f[0] = v.x; f[1] = v.y; f[2] = v.z; f[3] = v.w;
  } else {
#pragma unroll
    for (int j = 0; j < 4; ++j) {
      int cp = c4 + j;
      f[j] = src[(size_t)o * 1024 + (cp & 63) * 16 + (cp >> 6)];
    }
  }
  u32 p0 = (u32)f2bf(f[0]) | ((u32)f2bf(f[1]) << 16);
  u32 p1 = (u32)f2bf(f[2]) | ((u32)f2bf(f[3]) << 16);
  *(uint2*)(dst + (size_t)o * 1024 + c4) = make_uint2(p0, p1);
}

// ---------------------------------------------------------------------------
// GEMM v5 (4-buffer, 1 barrier/step): C[c,ng] = sum_k A[c,k]*B[ng,k] (+bias).
// BM=128, BN=256, BK=32, 8 waves (2M x 4N, wave-tile 64x64). Quad-buffered
// LDS (96 KB), prefetch depth 3, ONE s_waitcnt vmcnt(6) + ONE s_barrier per
// K-step, STAGE issued after the barrier (write target (t+3)&3 != read t&3,
// and post-barrier issue means all waves finished reading that buffer).
// Pair-row XOR swizzle (conflict-free ds_read_b128, rule #21 both-sides).
// XCD remap: xcd = bid&7 owns nt in [4*xcd, 4*xcd+4).
// EPI 0: bf16 -> Q/K [ng][h][d]  EPI 1: bf16 -> V [b][h][d][n]
// EPI 2: fp32 -> [b][c][n]
// grid 256 x 512 threads.
// ---------------------------------------------------------------------------
template <int EPI>
__global__ __launch_bounds__(512, 2) void gemm4b(const u16* __restrict__ A,
                                                 const u16* __restrict__ B,
                                                 const float* __restrict__ bias,
                                                 void* __restrict__ Out, float escale) {
  // u16 offsets: A bufs at buf*4096 (8KB each), B bufs at 16384 + buf*8192
  __shared__ u16 LD[49152];  // 96 KB
  int tid = threadIdx.x;
  int wave = tid >> 6, l = tid & 63, ln = l & 15, g = l >> 4;
  int wm = wave >> 2, wn = wave & 3;
  int bid = blockIdx.x;
  int mt = (bid >> 3) & 7;
  int nt = ((bid & 7) << 2) | (bid >> 6);
  int c0 = mt * 128, n0 = nt * 256;

  // staging source (pre-swizzled): thread i covers LDS 16B-slot i of the chunk
  int R = tid >> 3, sl = tid & 7;
  int v = sl ^ (R & 7);
  int sa = v >> 2, sg = v & 3;
  const u16* aSrc = A + (size_t)(c0 + 2 * R + sa) * 1024 + sg * 8;
  const u16* bSrc0 = B + (size_t)(n0 + 2 * R + sa) * 1024 + sg * 8;
  const u16* bSrc1 = B + (size_t)(n0 + 128 + 2 * R + sa) * 1024 + sg * 8;

  // fragment read offsets (u16 units): row X -> LDS row X>>1 (64 u16 each),
  // slot ((X&1)*4+g) ^ ((X>>1)&7); mm/nn-independent part:
  int slr = ((((ln & 1) << 2) | g) ^ ((ln >> 1) & 7)) * 8;
  int laneA = (wm * 32 + (ln >> 1)) * 64 + slr;
  int laneB = (wn * 32 + (ln >> 1)) * 64 + slr;

  f32x4 acc[4][4] = {};

#define STAGE(buf, kt)                                                   \
  do {                                                                   \
    gload_lds16(aSrc + (kt) * 32, &LD[(buf) * 4096 + tid * 8]);          \
    gload_lds16(bSrc0 + (kt) * 32, &LD[16384 + (buf) * 8192 + tid * 8]); \
    gload_lds16(bSrc1 + (kt) * 32,                                       \
                &LD[16384 + (buf) * 8192 + 4096 + tid * 8]);             \
  } while (0)

  STAGE(0, 0);
  STAGE(1, 1);
  STAGE(2, 2);

#pragma unroll
  for (int t = 0; t < 32; ++t) {
    if (t < 30)
      asm volatile("s_waitcnt vmcnt(6)" ::: "memory");
    else if (t == 30)
      asm volatile("s_waitcnt vmcnt(3)" ::: "memory");
    else
      asm volatile("s_waitcnt vmcnt(0)" ::: "memory");
    asm volatile("s_barrier" ::: "memory");
    if (t <= 28) STAGE((t + 3) & 3, t + 3);
    const int ab = (t & 3) * 4096;
    const int bb = 16384 + (t & 3) * 8192;
    bf16x8 af[4], bfr[4];
#pragma unroll
    for (int mm = 0; mm < 4; ++mm) af[mm] = *(const bf16x8*)&LD[ab + laneA + mm * 512];
#pragma unroll
    for (int nn = 0; nn < 4; ++nn) bfr[nn] = *(const bf16x8*)&LD[bb + laneB + nn * 512];
    __builtin_amdgcn_s_setprio(1);
#pragma unroll
    for (int mm = 0; mm < 4; ++mm)
#pragma unroll
      for (int nn = 0; nn < 4; ++nn)
        acc[mm][nn] = __builtin_amdgcn_mfma_f32_16x16x32_bf16(af[mm], bfr[nn], acc[mm][nn], 0, 0, 0);
    __builtin_amdgcn_s_setprio(0);
  }
#undef STAGE

  int D0 = (c0 >> 4) + wm * 4;
#pragma unroll
  for (int nn = 0; nn < 4; ++nn) {
    size_t ng = (size_t)n0 + wn * 64 + nn * 16 + ln;
#pragma unroll
    for (int r = 0; r < 4; ++r) {
      int h = g * 4 + r;
      if (EPI == 0) {
        bf16x4 pk;
#pragma unroll
        for (int mm = 0; mm < 4; ++mm) {
          int c = c0 + wm * 64 + mm * 16 + h;
          pk[mm] = (__bf16)((acc[mm][nn][r] + bias[c]) * escale);
        }
        *(bf16x4*)((u16*)Out + ng * 1024 + (size_t)h * 64 + D0) = pk;
      } else {
        size_t b = ng >> 10, n = ng & 1023;
#pragma unroll
        for (int mm = 0; mm < 4; ++mm) {
          int c = c0 + wm * 64 + mm * 16 + h;
          float val = (acc[mm][nn][r] + bias[c]) * escale;
          if (EPI == 1) {
            int d = D0 + mm;
            ((u16*)Out)[((b * 16 + h) * 64 + d) * 1024 + n] = f2bf(val);
          } else {
            ((float*)Out)[(b << 20) + (size_t)c * 1024 + n] = val;
          }
        }
      }
    }
  }
}

// ---------------------------------------------------------------------------
// Flash attention (unchanged): one block = (b,h, 128 q-rows).
// Q,K in [b][n][h][d], V in [b][h][d][n]. No-max exp2 softmax, K/V
// double-buffered via swizzled global_load_lds. Output [b][n][h*64+d].
// ---------------------------------------------------------------------------
__global__ __launch_bounds__(256) void attn_kernel(const u16* __restrict__ Qh,
                                                   const u16* __restrict__ Kh,
                                                   const u16* __restrict__ Vt,
                                                   u16* __restrict__ Xh) {
  __shared__ u16 Ks[2][4096];
  __shared__ u16 Vs[2][4096];
  __shared__ u16 Ps[8][16 * 72];
  int tid = threadIdx.x;
  int w = tid >> 6, l = tid & 63, ln = l & 15, g = l >> 4;
  int id = blockIdx.x;
  int qp = (id & 63) >> 3;
  int bh = ((id >> 6) << 3) | (id & 7);
  size_t b = bh >> 4;
  int h = bh & 15;
  const u16* Qg = Qh + (b << 20) + (h << 6);
  const u16* Kg = Kh + (b << 20) + (h << 6);
  const u16* Vg = Vt + ((size_t)bh << 16);
  u16* Og = Xh + (b << 20) + (h << 6);

  bf16x8 qf[2][2];
#pragma unroll
  for (int t = 0; t < 2; ++t)
#pragma unroll
    for (int kk = 0; kk < 2; ++kk)
      qf[t][kk] = *(const bf16x8*)(Qg + (size_t)(qp * 128 + t * 64 + w * 16 + ln) * 1024 + kk * 32 + g * 8);

  int lr = l >> 3;
  int sw8 = ((l & 7) ^ lr) << 3;
  int r0 = w * 16 + lr, r1 = r0 + 8;
  const u16* kS0 = Kg + (size_t)r0 * 1024 + sw8;
  const u16* kS1 = Kg + (size_t)r1 * 1024 + sw8;
  const u16* vS0 = Vg + (size_t)r0 * 1024 + sw8;
  const u16* vS1 = Vg + (size_t)r1 * 1024 + sw8;

  f32x4 xacc[2][4] = {};
  float lacc[2] = {0.f, 0.f};

  gload_lds16(kS0, &Ks[0][(w * 2) * 512]);
  gload_lds16(kS1, &Ks[0][(w * 2 + 1) * 512]);
  gload_lds16(vS0, &Vs[0][(w * 2) * 512]);
  gload_lds16(vS1, &Vs[0][(w * 2 + 1) * 512]);
  __syncthreads();

  int sx = ln & 7;
  int cur = 0;
  for (int kt = 0; kt < 16; ++kt) {
    if (kt < 15) {
      int nxt = cur ^ 1;
      gload_lds16(kS0 + (size_t)(kt + 1) * 65536, &Ks[nxt][(w * 2) * 512]);
      gload_lds16(kS1 + (size_t)(kt + 1) * 65536, &Ks[nxt][(w * 2 + 1) * 512]);
      gload_lds16(vS0 + (kt + 1) * 64, &Vs[nxt][(w * 2) * 512]);
      gload_lds16(vS1 + (kt + 1) * 64, &Vs[nxt][(w * 2 + 1) * 512]);
    }
    bf16x8 kf[2][4], vf[2][4];
#pragma unroll
    for (int kk = 0; kk < 2; ++kk)
#pragma unroll
      for (int f = 0; f < 4; ++f) {
        int slot = (((kk << 2) + g) ^ sx) << 3;
        kf[kk][f] = *(const bf16x8*)&Ks[cur][(f * 16 + ln) * 64 + slot];
        vf[kk][f] = *(const bf16x8*)&Vs[cur][(f * 16 + ln) * 64 + slot];
      }
    f32x4 sacc[2][4] = {};
#pragma unroll
    for (int t = 0; t < 2; ++t)
#pragma unroll
      for (int kk = 0; kk < 2; ++kk)
#pragma unroll
        for (int f = 0; f < 4; ++f)
          sacc[t][f] = __builtin_amdgcn_mfma_f32_16x16x32_bf16(kf[kk][f], qf[t][kk], sacc[t][f], 0, 0, 0);
#pragma unroll
    for (int t = 0; t < 2; ++t) {
      u16* PsW = Ps[w * 2 + t];
#pragma unroll
      for (int f = 0; f < 4; ++f) {
        float p0 = __builtin_amdgcn_exp2f(sacc[t][f][0]);
        float p1 = __builtin_amdgcn_exp2f(sacc[t][f][1]);
        float p2 = __builtin_amdgcn_exp2f(sacc[t][f][2]);
        float p3 = __builtin_amdgcn_exp2f(sacc[t][f][3]);
        lacc[t] += (p0 + p1) + (p2 + p3);
        bf16x4 pb;
        pb[0] = (__bf16)p0; pb[1] = (__bf16)p1; pb[2] = (__bf16)p2; pb[3] = (__bf16)p3;
        *(bf16x4*)&PsW[ln * 72 + (f << 4) + (g << 2)] = pb;
      }
    }
#pragma unroll
    for (int t = 0; t < 2; ++t) {
      const u16* PsR = Ps[w * 2 + t];
#pragma unroll
      for (int kk = 0; kk < 2; ++kk) {
        bf16x8 pf = *(const bf16x8*)&PsR[ln * 72 + (kk << 5) + (g << 3)];
#pragma unroll
        for (int fd = 0; fd < 4; ++fd)
          xacc[t][fd] = __builtin_amdgcn_mfma_f32_16x16x32_bf16(pf, vf[kk][fd], xacc[t][fd], 0, 0, 0);
      }
    }
    __syncthreads();
    cur ^= 1;
  }

#pragma unroll
  for (int t = 0; t < 2; ++t) {
    float lt = lacc[t];
    lt += __shfl_xor(lt, 16);
    lt += __shfl_xor(lt, 32);
    float il[4];
#pragma unroll
    for (int r = 0; r < 4; ++r) il[r] = 1.0f / __shfl(lt, g * 4 + r);
#pragma unroll
    for (int fd = 0; fd < 4; ++fd)
#pragma unroll
      for (int r = 0; r < 4; ++r) {
        int nq = qp * 128 + t * 64 + w * 16 + g * 4 + r;
        Og[(size_t)nq * 1024 + fd * 16 + ln] = f2bf(xacc[t][fd][r] * il[r]);
      }
  }
}

// ---------------------------------------------------------------------------
extern "C" void kernel_launch(void* const* d_in, const int* in_sizes, int n_in,
                              void* d_out, int out_size, void* d_ws, size_t ws_size,
                              hipStream_t stream) {
  const float* q  = (const float*)d_in[0];
  const float* k  = (const float*)d_in[1];
  const float* v  = (const float*)d_in[2];
  const float* Wq = (const float*)d_in[3];
  const float* bq = (const float*)d_in[4];
  const float* Wk = (const float*)d_in[5];
  const float* bk = (const float*)d_in[6];
  const float* Wv = (const float*)d_in[7];
  const float* bv = (const float*)d_in[8];
  const float* Wm = (const float*)d_in[9];
  const float* bm = (const float*)d_in[10];

  char* ws = (char*)d_ws;
  u16* Wbf = (u16*)ws;                      //  8 MB: Wq,Wk,Wv,Wm' bf16
  u16* Qh  = (u16*)(ws + (8ull << 20));     // 16 MB [b][n][h][d]
  u16* Kh  = (u16*)(ws + (24ull << 20));    // 16 MB [b][n][h][d]
  u16* Vt  = (u16*)(ws + (40ull << 20));    // 16 MB [b][h][d][n]
  u16* Xt  = (u16*)(ws + (56ull << 20));    // 16 MB, reused (X^T, then attn out)

  cast_weights<<<dim3(1024, 4, 1), 256, 0, stream>>>(Wq, Wk, Wv, Wm, Wbf);

  dim3 tg(16, 16, 8);
  const float qscale = 0.125f * 1.44269504088896340736f;  // 1/sqrt(64) * log2(e)

  transpose_cast<<<tg, 256, 0, stream>>>(q, Xt);
  gemm4b<0><<<256, 512, 0, stream>>>(Wbf, Xt, bq, Qh, qscale);
  transpose_cast<<<tg, 256, 0, stream>>>(k, Xt);
  gemm4b<0><<<256, 512, 0, stream>>>(Wbf + (1u << 20), Xt, bk, Kh, 1.0f);
  transpose_cast<<<tg, 256, 0, stream>>>(v, Xt);
  gemm4b<1><<<256, 512, 0, stream>>>(Wbf + (2u << 20), Xt, bv, Vt, 1.0f);

  attn_kernel<<<1024, 256, 0, stream>>>(Qh, Kh, Vt, Xt);

  gemm4b<2><<<256, 512, 0, stream>>>(Wbf + (3u << 20), Xt, bm, d_out, 1.0f);
}